// Round 9
// baseline (256.659 us; speedup 1.0000x reference)
//
#include <hip/hip_runtime.h>
#include <hip/hip_bf16.h>

// Encoder: B=4, S=2048, D=256, H=8, DK=32, DFF=1024, fp32 in/out.
// bf16 pipeline. Fixed-base softmax (scores>=0: ReLU'd q,k), l via
// ones-MFMA, fused normalize-in-epilogue attention (no combine pass),
// double-buffered GEMM with 64x64 wave tiles where N allows.

#define MROWS 8192   // B*S
#define DMODEL 256
#define SEQ 2048
#define LN_EPS 1e-5f

typedef float f32x4 __attribute__((ext_vector_type(4)));
typedef unsigned int u32x4 __attribute__((ext_vector_type(4)));

__device__ __forceinline__ unsigned pk2(float lo, float hi) {
  union { __hip_bfloat162 h; unsigned u; } c;
  c.h = __float22bfloat162_rn(make_float2(lo, hi));
  return c.u;
}
__device__ __forceinline__ unsigned short bf1(float f) {
  union { __hip_bfloat16 h; unsigned short u; } c;
  c.h = __float2bfloat16(f);
  return c.u;
}

__device__ __forceinline__ f32x4 mfma_bf16(u32x4 a, u32x4 b, f32x4 c) {
  asm volatile("v_mfma_f32_16x16x32_bf16 %0, %1, %2, %0"
               : "+v"(c) : "v"(a), "v"(b));
  return c;
}

__device__ __forceinline__ void gload_lds16(const void* g, void* l) {
  __builtin_amdgcn_global_load_lds(
      (const __attribute__((address_space(1))) void*)g,
      (__attribute__((address_space(3))) void*)l, 16, 0, 0);
}

// ---------------- fp32 -> bf16 batch convert ----------------
struct CvtArgs {
  const float* s[13];
  unsigned short* d[13];
  int n4[13];
};
__global__ __launch_bounds__(256) void cvt_kernel(CvtArgs a) {
  const int y = blockIdx.y;
  const int n4 = a.n4[y];
  const float4* src = (const float4*)a.s[y];
  unsigned short* dst = a.d[y];
  for (int i = blockIdx.x * 256 + threadIdx.x; i < n4; i += 256 * 256) {
    float4 v = src[i];
    uint2 o;
    o.x = pk2(v.x, v.y);
    o.y = pk2(v.z, v.w);
    *(uint2*)(dst + (size_t)i * 4) = o;
  }
}

// ---------------- bf16 MFMA GEMM: relu(A @ W^T) (+res) ----------------
// BM=128, BK=64, 4 waves (2x2). BN=128: wave 64x64 (acc 4x4, read:mfma
// 0.5); BN=64: wave 64x32 (acc 4x2). Double-buffered, global_load_lds
// with source-swizzle slot^=(row&7). Fused-QKV epilogue when outB2 set.
template <int BN>
__global__ __launch_bounds__(256) void gemm_bf16_kernel(
    const unsigned short* __restrict__ A, const unsigned short* __restrict__ W,
    const float* __restrict__ res, float* __restrict__ outF,
    unsigned short* __restrict__ outB, unsigned short* __restrict__ outB2,
    unsigned short* __restrict__ outVT, float bscale, int N, int K, int ntx) {
  constexpr int NF = BN / 32;  // n-frags per wave
  __shared__ alignas(16) unsigned short As[2][128 * 64];
  __shared__ alignas(16) unsigned short Ws[2][BN * 64];
  const int tid = threadIdx.x;
  const int w = tid >> 6, lane = tid & 63;
  const int lq = lane & 15, kg = lane >> 4;
  const int wm = w >> 1, wn = w & 1;
  const int nwg = gridDim.x, cpx = nwg >> 3, bid = blockIdx.x;
  const int lid = (bid & 7) * cpx + (bid >> 3);
  const int m0 = (lid / ntx) * 128, n0 = (lid % ntx) * BN;

  f32x4 acc[4][NF] = {};

  auto STAGE = [&](int buf, int k0) {
#pragma unroll
    for (int i = 0; i < 4; i++) {  // A: 128 rows x 8 slots
      const int li = i * 256 + tid;
      const int row = li >> 3, sl = (li & 7) ^ (row & 7);
      gload_lds16(A + (size_t)(m0 + row) * K + k0 + sl * 8,
                  (char*)As[buf] + (i * 256 + (tid & ~63)) * 16);
    }
#pragma unroll
    for (int i = 0; i < BN / 32; i++) {  // W: BN rows x 8 slots
      const int li = i * 256 + tid;
      const int row = li >> 3, sl = (li & 7) ^ (row & 7);
      gload_lds16(W + (size_t)(n0 + row) * K + k0 + sl * 8,
                  (char*)Ws[buf] + (i * 256 + (tid & ~63)) * 16);
    }
  };

  const int nt = K >> 6;
  STAGE(0, 0);
  for (int t = 0; t < nt; t++) {
    __syncthreads();  // drains vmcnt: buf[t&1] ready
    if (t + 1 < nt) STAGE((t + 1) & 1, (t + 1) << 6);
    const unsigned short* as = As[t & 1];
    const unsigned short* wsb = Ws[t & 1];
#pragma unroll
    for (int kk = 0; kk < 2; kk++) {
      const int sl = (((kk * 4 + kg) ^ (lq & 7)) << 3);
      u32x4 af[4], bf[NF];
#pragma unroll
      for (int mi = 0; mi < 4; mi++)
        af[mi] = *(const u32x4*)&as[((wm * 64 + mi * 16 + lq) << 6) + sl];
#pragma unroll
      for (int nj = 0; nj < NF; nj++)
        bf[nj] = *(const u32x4*)&wsb[((wn * (BN / 2) + nj * 16 + lq) << 6) + sl];
      __builtin_amdgcn_s_setprio(1);
#pragma unroll
      for (int mi = 0; mi < 4; mi++)
#pragma unroll
        for (int nj = 0; nj < NF; nj++)
          acc[mi][nj] = mfma_bf16(af[mi], bf[nj], acc[mi][nj]);
      __builtin_amdgcn_s_setprio(0);
    }
  }

  // Epilogue: D row = kg*4+r, col = lq per 16x16 frag.
  if (outB2) {  // fused QKV (BN=128, N=768): q|k|v by column region
#pragma unroll
    for (int mi = 0; mi < 4; mi++) {
      const int m = m0 + wm * 64 + mi * 16 + kg * 4;
#pragma unroll
      for (int nj = 0; nj < NF; nj++) {
        const int nb_ = n0 + wn * (BN / 2) + nj * 16;
        const int reg = nb_ >> 8;
        if (reg == 0) {
          const int n = nb_ + lq;
#pragma unroll
          for (int r = 0; r < 4; r++)
            outB[(size_t)(m + r) * 256 + n] =
                bf1(fmaxf(acc[mi][nj][r], 0.f) * bscale);
        } else if (reg == 1) {
          const int n = nb_ - 256 + lq;
#pragma unroll
          for (int r = 0; r < 4; r++)
            outB2[(size_t)(m + r) * 256 + n] = bf1(fmaxf(acc[mi][nj][r], 0.f));
        } else {  // V^T: [b*8+h][d][s]
          const int nn = nb_ - 512 + lq;
          const int hh = nn >> 5, dd = nn & 31;
          const int bq = m >> 11, s0 = m & 2047;
          uint2 pv;
          pv.x = pk2(fmaxf(acc[mi][nj][0], 0.f), fmaxf(acc[mi][nj][1], 0.f));
          pv.y = pk2(fmaxf(acc[mi][nj][2], 0.f), fmaxf(acc[mi][nj][3], 0.f));
          *(uint2*)(outVT + ((size_t)(bq * 8 + hh) * 32 + dd) * 2048 + s0) = pv;
        }
      }
    }
  } else {
#pragma unroll
    for (int mi = 0; mi < 4; mi++) {
      const int m = m0 + wm * 64 + mi * 16 + kg * 4;
#pragma unroll
      for (int nj = 0; nj < NF; nj++) {
        const int n = n0 + wn * (BN / 2) + nj * 16 + lq;
#pragma unroll
        for (int r = 0; r < 4; r++) {
          float v = fmaxf(acc[mi][nj][r], 0.f);
          if (res) v += res[(size_t)(m + r) * N + n];
          if (outF) outF[(size_t)(m + r) * N + n] = v;
          if (outB) outB[(size_t)(m + r) * N + n] = bf1(v);
        }
      }
    }
  }
}

// ---------------- MFMA flash attention, fixed-base softmax ----------------
// 4 waves x 32 q rows (2 q-frags), 64 keys/step, double-buffered K/V,
// normalize fused in epilogue (single KV pass, no combine).
__global__ __launch_bounds__(256) void attn_mfma_kernel(
    const unsigned short* __restrict__ Q, const unsigned short* __restrict__ K,
    const unsigned short* __restrict__ VT, unsigned short* __restrict__ O) {
  __shared__ alignas(16) unsigned short Ks[2][64 * 32];  // [key][4 slots x 8]
  __shared__ alignas(16) unsigned short Vt[2][32 * 64];  // [d][8 slots x 8]
  __shared__ alignas(16) unsigned short Ps[4][32][72];

  const int tid = threadIdx.x;
  const int w = tid >> 6;
  const int lane = tid & 63;
  const int lq = lane & 15;
  const int kg = lane >> 4;
  const int bh = blockIdx.y, b = bh >> 3, h = bh & 7;
  const int q0 = blockIdx.x * 128 + w * 32;
  const size_t base = (size_t)b * SEQ * DMODEL + h * 32;

  u32x4 qf[2];
  qf[0] = *(const u32x4*)(Q + base + (size_t)(q0 + lq) * DMODEL + kg * 8);
  qf[1] = *(const u32x4*)(Q + base + (size_t)(q0 + 16 + lq) * DMODEL + kg * 8);

  f32x4 oLo[2] = {{0.f, 0.f, 0.f, 0.f}, {0.f, 0.f, 0.f, 0.f}};  // d=kg*4+r
  f32x4 oHi[2] = {{0.f, 0.f, 0.f, 0.f}, {0.f, 0.f, 0.f, 0.f}};  // d=16+..
  f32x4 lac[2] = {{0.f, 0.f, 0.f, 0.f}, {0.f, 0.f, 0.f, 0.f}};
  const unsigned ONE2 = 0x3F803F80u;
  const u32x4 ones = {ONE2, ONE2, ONE2, ONE2};

  const int kg4 = (lane & 3) ^ ((lane >> 3) & 3);  // K src slot swizzle
  const int vg8 = (lane & 7) ^ (lane >> 3);        // V src slot swizzle
  const unsigned short* vtb = VT + (size_t)bh * 32 * 2048;
  const int kslot = (lq >> 1) & 3;
  const int vslot = lq & 7;

  auto STAGE = [&](int buf, int kt) {
    const int krow = w * 16 + (lane >> 2);
    gload_lds16(K + base + (size_t)(kt + krow) * DMODEL + kg4 * 8,
                (char*)Ks[buf] + w * 1024);
    const int d = w * 8 + (lane >> 3);
    gload_lds16(vtb + (size_t)d * 2048 + kt + vg8 * 8,
                (char*)Vt[buf] + w * 1024);
  };

  const int nt = SEQ >> 6;
  STAGE(0, 0);
  for (int t = 0; t < nt; t++) {
    __syncthreads();
    if (t + 1 < nt) STAGE((t + 1) & 1, (t + 1) * 64);
    const unsigned short* ks = Ks[t & 1];
    const unsigned short* vs = Vt[t & 1];

    // shared K fragments (A operand: rows=keys)
    u32x4 ka[4];
#pragma unroll
    for (int s4 = 0; s4 < 4; s4++)
      ka[s4] =
          *(const u32x4*)&ks[((s4 * 16 + lq) << 5) + ((kg ^ kslot) << 3)];

#pragma unroll
    for (int f = 0; f < 2; f++) {
      f32x4 sc[4];
      __builtin_amdgcn_s_setprio(1);
#pragma unroll
      for (int s4 = 0; s4 < 4; s4++) {
        f32x4 z = {0.f, 0.f, 0.f, 0.f};
        sc[s4] = mfma_bf16(ka[s4], qf[f], z);
      }
      __builtin_amdgcn_s_setprio(0);
      // P = exp2(sc) directly (sc >= 0; base cancels in o/l)
#pragma unroll
      for (int s4 = 0; s4 < 4; s4++) {
        uint2 pw;
        pw.x = pk2(exp2f(sc[s4][0]), exp2f(sc[s4][1]));
        pw.y = pk2(exp2f(sc[s4][2]), exp2f(sc[s4][3]));
        *(uint2*)&Ps[w][f * 16 + lq][s4 * 16 + kg * 4] = pw;
      }
    }

    u32x4 va00 = *(const u32x4*)&vs[(lq << 6) + ((kg ^ vslot) << 3)];
    u32x4 va01 = *(const u32x4*)&vs[(lq << 6) + (((4 | kg) ^ vslot) << 3)];
    u32x4 va10 = *(const u32x4*)&vs[((16 + lq) << 6) + ((kg ^ vslot) << 3)];
    u32x4 va11 = *(const u32x4*)&vs[((16 + lq) << 6) + (((4 | kg) ^ vslot) << 3)];
#pragma unroll
    for (int f = 0; f < 2; f++) {
      u32x4 pf0 = *(const u32x4*)&Ps[w][f * 16 + lq][kg * 8];
      u32x4 pf1 = *(const u32x4*)&Ps[w][f * 16 + lq][32 + kg * 8];
      __builtin_amdgcn_s_setprio(1);
      oLo[f] = mfma_bf16(va00, pf0, oLo[f]);
      oLo[f] = mfma_bf16(va01, pf1, oLo[f]);
      oHi[f] = mfma_bf16(va10, pf0, oHi[f]);
      oHi[f] = mfma_bf16(va11, pf1, oHi[f]);
      lac[f] = mfma_bf16(ones, pf0, lac[f]);
      lac[f] = mfma_bf16(ones, pf1, lac[f]);
      __builtin_amdgcn_s_setprio(0);
    }
  }

  // Epilogue: normalize and write bf16 O[qrow][h*32+d], d=r-consecutive.
#pragma unroll
  for (int f = 0; f < 2; f++) {
    const float inv = 1.f / lac[f][0];
    const int qrow = q0 + f * 16 + lq;
    unsigned short* op = O + (size_t)b * SEQ * DMODEL + (size_t)qrow * DMODEL +
                         h * 32;
    uint2 vlo, vhi;
    vlo.x = pk2(oLo[f][0] * inv, oLo[f][1] * inv);
    vlo.y = pk2(oLo[f][2] * inv, oLo[f][3] * inv);
    vhi.x = pk2(oHi[f][0] * inv, oHi[f][1] * inv);
    vhi.y = pk2(oHi[f][2] * inv, oHi[f][3] * inv);
    *(uint2*)(op + kg * 4) = vlo;
    *(uint2*)(op + 16 + kg * 4) = vhi;
  }
}

// ---------------- LayerNorm (256) ----------------
__global__ __launch_bounds__(256) void ln_kernel(
    const float* __restrict__ X, const float* __restrict__ g,
    const float* __restrict__ b, float* __restrict__ Y,
    unsigned short* __restrict__ Yb) {
  const int wid = (blockIdx.x * blockDim.x + threadIdx.x) >> 6;
  const int lane = threadIdx.x & 63;
  const float* x = X + (size_t)wid * DMODEL;
  float4 v = *(const float4*)(x + lane * 4);
  float s = v.x + v.y + v.z + v.w;
  float s2 = v.x * v.x + v.y * v.y + v.z * v.z + v.w * v.w;
#pragma unroll
  for (int off = 32; off >= 1; off >>= 1) {
    s += __shfl_xor(s, off, 64);
    s2 += __shfl_xor(s2, off, 64);
  }
  const float mu = s * (1.f / DMODEL);
  const float var = s2 * (1.f / DMODEL) - mu * mu;
  const float inv = rsqrtf(var + LN_EPS);
  float4 gv = *(const float4*)(g + lane * 4);
  float4 bv = *(const float4*)(b + lane * 4);
  float4 o;
  o.x = (v.x - mu) * inv * gv.x + bv.x;
  o.y = (v.y - mu) * inv * gv.y + bv.y;
  o.z = (v.z - mu) * inv * gv.z + bv.z;
  o.w = (v.w - mu) * inv * gv.w + bv.w;
  if (Y) *(float4*)(Y + (size_t)wid * DMODEL + lane * 4) = o;
  if (Yb) {
    uint2 p;
    p.x = pk2(o.x, o.y);
    p.y = pk2(o.z, o.w);
    *(uint2*)(Yb + (size_t)wid * DMODEL + lane * 4) = p;
  }
}

extern "C" void kernel_launch(void* const* d_in, const int* in_sizes, int n_in,
                              void* d_out, int out_size, void* d_ws, size_t ws_size,
                              hipStream_t stream) {
  const float* x = (const float*)d_in[0];
  const float* g1 = (const float*)d_in[13];
  const float* b1 = (const float*)d_in[14];
  const float* g2 = (const float*)d_in[15];
  const float* b2 = (const float*)d_in[16];
  const float* g3 = (const float*)d_in[17];
  const float* b3 = (const float*)d_in[18];
  const float* g4 = (const float*)d_in[19];
  const float* b4 = (const float*)d_in[20];

  float* out = (float*)d_out;
  float* ws = (float*)d_ws;
  const size_t NM = (size_t)MROWS * DMODEL;
  const float QSCALE = 0.17677669529663687f * 1.4426950408889634f;

  float* F0 = ws;
  float* F1 = ws + NM;
  unsigned short* fb = (unsigned short*)(ws + 2 * NM);  // 8192x1024 bf16
  unsigned short* xb = fb + 4 * NM;
  unsigned short* qb = xb + NM;
  unsigned short* kb = qb + NM;
  unsigned short* ob = kb + NM;
  unsigned short* nb = ob + NM;
  unsigned short* wb = nb + NM;
  unsigned short* qkv1 = wb;
  unsigned short* qkv2 = wb + 3 * 65536;
  unsigned short* o1w = wb + 6 * 65536;
  unsigned short* o2w = wb + 7 * 65536;
  unsigned short* f11 = wb + 8 * 65536;
  unsigned short* f21 = f11 + 262144;
  unsigned short* f12 = f21 + 262144;
  unsigned short* f22 = f12 + 262144;
  unsigned short* vt = (unsigned short*)F0;  // aliases F0 (dead then)

  {
    CvtArgs a;
    a.s[0] = x; a.d[0] = xb; a.n4[0] = (int)(NM / 4);
    unsigned short* wd[12] = {qkv1, qkv1 + 65536, qkv1 + 131072, o1w,
                              qkv2, qkv2 + 65536, qkv2 + 131072, o2w,
                              f11, f21, f12, f22};
    for (int i = 0; i < 12; i++) {
      a.s[i + 1] = (const float*)d_in[i + 1];
      a.d[i + 1] = wd[i];
      a.n4[i + 1] = (i < 8) ? 65536 / 4 : 262144 / 4;
    }
    cvt_kernel<<<dim3(256, 13), 256, 0, stream>>>(a);
  }

  // gemm launchers: BN=128 (wave 64x64) and BN=64 (wave 64x32)
  auto gemm128 = [&](const unsigned short* A, const unsigned short* W,
                     unsigned short* oB, unsigned short* oB2,
                     unsigned short* oVT, float bs, int N, int K) {
    const int ntx = N / 128;
    gemm_bf16_kernel<128><<<ntx * (MROWS / 128), 256, 0, stream>>>(
        A, W, nullptr, nullptr, oB, oB2, oVT, bs, N, K, ntx);
  };
  auto gemm64 = [&](const unsigned short* A, const unsigned short* W,
                    const float* res, float* oF, unsigned short* oB,
                    int N, int K) {
    const int ntx = N / 64;
    gemm_bf16_kernel<64><<<ntx * (MROWS / 128), 256, 0, stream>>>(
        A, W, res, oF, oB, nullptr, nullptr, 1.f, N, K, ntx);
  };
  auto attn = [&](const unsigned short* Q, const unsigned short* K,
                  const unsigned short* VT, unsigned short* O) {
    attn_mfma_kernel<<<dim3(SEQ / 128, 32), 256, 0, stream>>>(Q, K, VT, O);
  };
  auto ln = [&](const float* X, const float* gm, const float* bt, float* Y,
                unsigned short* Yb) {
    ln_kernel<<<MROWS / 4, 256, 0, stream>>>(X, gm, bt, Y, Yb);
  };

  // ---- Block 1 ----
  gemm128(xb, qkv1, qb, kb, vt, QSCALE, 768, 256);   // fused QKV
  attn(qb, kb, vt, ob);
  gemm64(ob, o1w, x, F0, nullptr, 256, 256);         // x1 = relu(o@Wo)+x
  ln(F0, g1, b1, F1, nb);
  gemm128(nb, f11, fb, nullptr, nullptr, 1.f, 1024, 256);
  gemm64(fb, f21, F1, F0, nullptr, 256, 1024);       // x2
  ln(F0, g2, b2, F1, xb);

  // ---- Block 2 ----
  gemm128(xb, qkv2, qb, kb, vt, QSCALE, 768, 256);
  attn(qb, kb, vt, ob);
  gemm64(ob, o2w, F1, F0, nullptr, 256, 256);
  ln(F0, g3, b3, F1, nb);
  gemm128(nb, f12, fb, nullptr, nullptr, 1.f, 1024, 256);
  gemm64(fb, f22, F1, F0, nullptr, 256, 1024);
  ln(F0, g4, b4, out, nullptr);
}

// Round 10
// 247.398 us; speedup vs baseline: 1.0374x; 1.0374x over previous
//
#include <hip/hip_runtime.h>
#include <hip/hip_bf16.h>

// Encoder: B=4, S=2048, D=256, H=8, DK=32, DFF=1024, fp32 in/out.
// bf16 pipeline. Fixed-base softmax (scores>=0: ReLU'd q,k), l via
// ones-MFMA. Attn: 32q/wave + KV-split2 + combine. GEMM: 64x64/4-wave dbuf.

#define MROWS 8192   // B*S
#define DMODEL 256
#define SEQ 2048
#define LN_EPS 1e-5f

typedef float f32x4 __attribute__((ext_vector_type(4)));
typedef unsigned int u32x4 __attribute__((ext_vector_type(4)));

__device__ __forceinline__ unsigned pk2(float lo, float hi) {
  union { __hip_bfloat162 h; unsigned u; } c;
  c.h = __float22bfloat162_rn(make_float2(lo, hi));
  return c.u;
}
__device__ __forceinline__ unsigned short bf1(float f) {
  union { __hip_bfloat16 h; unsigned short u; } c;
  c.h = __float2bfloat16(f);
  return c.u;
}

__device__ __forceinline__ f32x4 mfma_bf16(u32x4 a, u32x4 b, f32x4 c) {
  asm volatile("v_mfma_f32_16x16x32_bf16 %0, %1, %2, %0"
               : "+v"(c) : "v"(a), "v"(b));
  return c;
}

__device__ __forceinline__ void gload_lds16(const void* g, void* l) {
  __builtin_amdgcn_global_load_lds(
      (const __attribute__((address_space(1))) void*)g,
      (__attribute__((address_space(3))) void*)l, 16, 0, 0);
}

// ---------------- fp32 -> bf16 batch convert ----------------
struct CvtArgs {
  const float* s[13];
  unsigned short* d[13];
  int n4[13];
};
__global__ __launch_bounds__(256) void cvt_kernel(CvtArgs a) {
  const int y = blockIdx.y;
  const int n4 = a.n4[y];
  const float4* src = (const float4*)a.s[y];
  unsigned short* dst = a.d[y];
  for (int i = blockIdx.x * 256 + threadIdx.x; i < n4; i += 256 * 256) {
    float4 v = src[i];
    uint2 o;
    o.x = pk2(v.x, v.y);
    o.y = pk2(v.z, v.w);
    *(uint2*)(dst + (size_t)i * 4) = o;
  }
}

// ---------------- bf16 MFMA GEMM: relu(A @ W^T) (+res) ----------------
// 256 threads, 4 waves (2x2), block 64x64, wave 32x32, BK=64, double-buffer
// LDS staged via global_load_lds (linear dest, pre-swizzled source).
// Fused-QKV epilogue: n0<256 -> outB (bscale), [256,512) -> outB2,
// >=512 -> outVT (V^T [b*8+h][d][s]). XCD-swizzled 1D grid.
__global__ __launch_bounds__(256) void gemm_bf16_kernel(
    const unsigned short* __restrict__ A, const unsigned short* __restrict__ W,
    const float* __restrict__ res, float* __restrict__ outF,
    unsigned short* __restrict__ outB, unsigned short* __restrict__ outB2,
    unsigned short* __restrict__ outVT, float bscale, int N, int K, int ntx) {
  __shared__ alignas(16) unsigned short As[2][64 * 64];
  __shared__ alignas(16) unsigned short Ws[2][64 * 64];
  const int tid = threadIdx.x;
  const int w = tid >> 6, lane = tid & 63;
  const int lq = lane & 15, kg = lane >> 4;
  const int wm = w >> 1, wn = w & 1;
  const int nwg = gridDim.x, cpx = nwg >> 3, bid = blockIdx.x;
  const int lid = (bid & 7) * cpx + (bid >> 3);
  const int m0 = (lid / ntx) * 64, n0 = (lid % ntx) * 64;

  f32x4 acc[2][2] = {};

  auto STAGE = [&](int buf, int k0) {
#pragma unroll
    for (int i = 0; i < 2; i++) {
      const int li = i * 256 + tid;
      const int row = li >> 3, sl = (li & 7) ^ (row & 7);
      gload_lds16(A + (size_t)(m0 + row) * K + k0 + sl * 8,
                  (char*)As[buf] + (i * 256 + (tid & ~63)) * 16);
    }
#pragma unroll
    for (int i = 0; i < 2; i++) {
      const int li = i * 256 + tid;
      const int row = li >> 3, sl = (li & 7) ^ (row & 7);
      gload_lds16(W + (size_t)(n0 + row) * K + k0 + sl * 8,
                  (char*)Ws[buf] + (i * 256 + (tid & ~63)) * 16);
    }
  };

  const int nt = K >> 6;
  STAGE(0, 0);
  for (int t = 0; t < nt; t++) {
    __syncthreads();  // drains vmcnt: buf[t&1] ready
    if (t + 1 < nt) STAGE((t + 1) & 1, (t + 1) << 6);
    const unsigned short* as = As[t & 1];
    const unsigned short* wsb = Ws[t & 1];
#pragma unroll
    for (int kk = 0; kk < 2; kk++) {
      const int sl = (((kk * 4 + kg) ^ (lq & 7)) << 3);
      u32x4 a0 = *(const u32x4*)&as[((wm * 32 + lq) << 6) + sl];
      u32x4 a1 = *(const u32x4*)&as[((wm * 32 + 16 + lq) << 6) + sl];
      u32x4 b0 = *(const u32x4*)&wsb[((wn * 32 + lq) << 6) + sl];
      u32x4 b1 = *(const u32x4*)&wsb[((wn * 32 + 16 + lq) << 6) + sl];
      __builtin_amdgcn_s_setprio(1);
      acc[0][0] = mfma_bf16(a0, b0, acc[0][0]);
      acc[0][1] = mfma_bf16(a0, b1, acc[0][1]);
      acc[1][0] = mfma_bf16(a1, b0, acc[1][0]);
      acc[1][1] = mfma_bf16(a1, b1, acc[1][1]);
      __builtin_amdgcn_s_setprio(0);
    }
  }

  // Epilogue: D row = kg*4+r, col = lq per 16x16 frag.
  if (outVT && n0 >= 512) {  // V^T path (fused QKV)
#pragma unroll
    for (int mi = 0; mi < 2; mi++) {
      const int mb = m0 + wm * 32 + mi * 16 + kg * 4;
      const int bq = mb >> 11, s0 = mb & 2047;
#pragma unroll
      for (int nj = 0; nj < 2; nj++) {
        const int nn = n0 - 512 + wn * 32 + nj * 16 + lq;
        const int hh = nn >> 5, dd = nn & 31;
        uint2 pv;
        pv.x = pk2(fmaxf(acc[mi][nj][0], 0.f), fmaxf(acc[mi][nj][1], 0.f));
        pv.y = pk2(fmaxf(acc[mi][nj][2], 0.f), fmaxf(acc[mi][nj][3], 0.f));
        *(uint2*)(outVT + ((size_t)(bq * 8 + hh) * 32 + dd) * 2048 + s0) = pv;
      }
    }
  } else if (outB2 && n0 >= 256) {  // K path (fused QKV)
#pragma unroll
    for (int mi = 0; mi < 2; mi++) {
      const int m = m0 + wm * 32 + mi * 16 + kg * 4;
#pragma unroll
      for (int nj = 0; nj < 2; nj++) {
        const int nn = n0 - 256 + wn * 32 + nj * 16 + lq;
#pragma unroll
        for (int r = 0; r < 4; r++)
          outB2[(size_t)(m + r) * 256 + nn] = bf1(fmaxf(acc[mi][nj][r], 0.f));
      }
    }
  } else {
    const int ldo = (outB2 || outVT) ? 256 : N;  // fused-Q path uses 256
#pragma unroll
    for (int mi = 0; mi < 2; mi++) {
      const int m = m0 + wm * 32 + mi * 16 + kg * 4;
#pragma unroll
      for (int nj = 0; nj < 2; nj++) {
        const int n = n0 + wn * 32 + nj * 16 + lq;
#pragma unroll
        for (int r = 0; r < 4; r++) {
          float v = fmaxf(acc[mi][nj][r], 0.f);
          if (res) v += res[(size_t)(m + r) * N + n];
          if (outF) outF[(size_t)(m + r) * N + n] = v;
          if (outB) outB[(size_t)(m + r) * ldo + n] = bf1(v * bscale);
        }
      }
    }
  }
}

// ---------------- MFMA flash attention, fixed-base softmax ----------------
// 4 waves x 32 q rows (2 q-frags), 64 keys/step, double-buffered K/V,
// KV-split via blockIdx.z; unnormalized o + l partials out.
__global__ __launch_bounds__(256) void attn_mfma_kernel(
    const unsigned short* __restrict__ Q, const unsigned short* __restrict__ K,
    const unsigned short* __restrict__ VT, float* __restrict__ oP,
    float* __restrict__ lP, int nkeys) {
  __shared__ alignas(16) unsigned short Ks[2][64 * 32];  // [key][4 slots x 8]
  __shared__ alignas(16) unsigned short Vt[2][32 * 64];  // [d][8 slots x 8]
  __shared__ alignas(16) unsigned short Ps[4][32][72];

  const int tid = threadIdx.x;
  const int w = tid >> 6;
  const int lane = tid & 63;
  const int lq = lane & 15;
  const int kg = lane >> 4;
  const int bh = blockIdx.y, b = bh >> 3, h = bh & 7;
  const int p = blockIdx.z;
  const int q0 = blockIdx.x * 128 + w * 32;
  const size_t base = (size_t)b * SEQ * DMODEL + h * 32;

  u32x4 qf[2];
  qf[0] = *(const u32x4*)(Q + base + (size_t)(q0 + lq) * DMODEL + kg * 8);
  qf[1] = *(const u32x4*)(Q + base + (size_t)(q0 + 16 + lq) * DMODEL + kg * 8);

  f32x4 oLo[2] = {{0.f, 0.f, 0.f, 0.f}, {0.f, 0.f, 0.f, 0.f}};
  f32x4 oHi[2] = {{0.f, 0.f, 0.f, 0.f}, {0.f, 0.f, 0.f, 0.f}};
  f32x4 lac[2] = {{0.f, 0.f, 0.f, 0.f}, {0.f, 0.f, 0.f, 0.f}};
  const unsigned ONE2 = 0x3F803F80u;
  const u32x4 ones = {ONE2, ONE2, ONE2, ONE2};

  const int kg4 = (lane & 3) ^ ((lane >> 3) & 3);  // K src slot swizzle
  const int vg8 = (lane & 7) ^ (lane >> 3);        // V src slot swizzle
  const unsigned short* vtb = VT + (size_t)bh * 32 * 2048;
  const int kslot = (lq >> 1) & 3;
  const int vslot = lq & 7;

  auto STAGE = [&](int buf, int kt) {
    const int krow = w * 16 + (lane >> 2);
    gload_lds16(K + base + (size_t)(kt + krow) * DMODEL + kg4 * 8,
                (char*)Ks[buf] + w * 1024);
    const int d = w * 8 + (lane >> 3);
    gload_lds16(vtb + (size_t)d * 2048 + kt + vg8 * 8,
                (char*)Vt[buf] + w * 1024);
  };

  const int kbeg = p * nkeys;
  const int nt = nkeys >> 6;
  STAGE(0, kbeg);
  for (int t = 0; t < nt; t++) {
    __syncthreads();
    if (t + 1 < nt) STAGE((t + 1) & 1, kbeg + (t + 1) * 64);
    const unsigned short* ks = Ks[t & 1];
    const unsigned short* vs = Vt[t & 1];

    u32x4 ka[4];
#pragma unroll
    for (int s4 = 0; s4 < 4; s4++)
      ka[s4] = *(const u32x4*)&ks[((s4 * 16 + lq) << 5) + ((kg ^ kslot) << 3)];

    // QK^T both q-frags first: 8 independent MFMAs in flight
    f32x4 sc[2][4];
    __builtin_amdgcn_s_setprio(1);
#pragma unroll
    for (int f = 0; f < 2; f++)
#pragma unroll
      for (int s4 = 0; s4 < 4; s4++) {
        f32x4 z = {0.f, 0.f, 0.f, 0.f};
        sc[f][s4] = mfma_bf16(ka[s4], qf[f], z);
      }
    __builtin_amdgcn_s_setprio(0);

    // P = exp2(sc) (sc >= 0; base cancels in o/l), pack, stash per-wave
#pragma unroll
    for (int f = 0; f < 2; f++)
#pragma unroll
      for (int s4 = 0; s4 < 4; s4++) {
        uint2 pw;
        pw.x = pk2(exp2f(sc[f][s4][0]), exp2f(sc[f][s4][1]));
        pw.y = pk2(exp2f(sc[f][s4][2]), exp2f(sc[f][s4][3]));
        *(uint2*)&Ps[w][f * 16 + lq][s4 * 16 + kg * 4] = pw;
      }

    u32x4 va00 = *(const u32x4*)&vs[(lq << 6) + ((kg ^ vslot) << 3)];
    u32x4 va01 = *(const u32x4*)&vs[(lq << 6) + (((4 | kg) ^ vslot) << 3)];
    u32x4 va10 = *(const u32x4*)&vs[((16 + lq) << 6) + ((kg ^ vslot) << 3)];
    u32x4 va11 = *(const u32x4*)&vs[((16 + lq) << 6) + (((4 | kg) ^ vslot) << 3)];
#pragma unroll
    for (int f = 0; f < 2; f++) {
      u32x4 pf0 = *(const u32x4*)&Ps[w][f * 16 + lq][kg * 8];
      u32x4 pf1 = *(const u32x4*)&Ps[w][f * 16 + lq][32 + kg * 8];
      __builtin_amdgcn_s_setprio(1);
      oLo[f] = mfma_bf16(va00, pf0, oLo[f]);
      oLo[f] = mfma_bf16(va01, pf1, oLo[f]);
      oHi[f] = mfma_bf16(va10, pf0, oHi[f]);
      oHi[f] = mfma_bf16(va11, pf1, oHi[f]);
      lac[f] = mfma_bf16(ones, pf0, lac[f]);
      lac[f] = mfma_bf16(ones, pf1, lac[f]);
      __builtin_amdgcn_s_setprio(0);
    }
  }

  // Partials out: unnormalized o + l (fixed base -> combine just sums)
#pragma unroll
  for (int f = 0; f < 2; f++) {
    const int qrow = q0 + f * 16 + lq;
    const size_t sidx = ((size_t)p * 32 + bh) * SEQ + qrow;
    if (kg == 0) lP[sidx] = lac[f][0];
    float* op = oP + sidx * 32;
    f32x4 lo = oLo[f], hi = oHi[f];
    *(f32x4*)(op + kg * 4) = lo;
    *(f32x4*)(op + 16 + kg * 4) = hi;
  }
}

// Merge 2 partial states: out = (o0+o1) / (l0+l1), write bf16
__global__ __launch_bounds__(256) void attn_combine_kernel(
    const float* __restrict__ oP, const float* __restrict__ lP,
    unsigned short* __restrict__ O) {
  const int t = blockIdx.x * blockDim.x + threadIdx.x;
  const int bh = t >> 11;
  const int qrow = t & 2047;
  const int b = bh >> 3, h = bh & 7;

  const size_t s0 = (size_t)bh * SEQ + qrow;
  const size_t s1 = ((size_t)32 + bh) * SEQ + qrow;
  const float inv = 1.f / (lP[s0] + lP[s1]);

  const float* o0 = oP + s0 * 32;
  const float* o1 = oP + s1 * 32;
  unsigned short* outp =
      O + (size_t)b * SEQ * DMODEL + (size_t)qrow * DMODEL + h * 32;
#pragma unroll
  for (int i = 0; i < 8; i++) {
    float4 a = *(const float4*)(o0 + i * 4);
    float4 c = *(const float4*)(o1 + i * 4);
    uint2 v;
    v.x = pk2((a.x + c.x) * inv, (a.y + c.y) * inv);
    v.y = pk2((a.z + c.z) * inv, (a.w + c.w) * inv);
    *(uint2*)(outp + i * 4) = v;
  }
}

// ---------------- LayerNorm (256) ----------------
__global__ __launch_bounds__(256) void ln_kernel(
    const float* __restrict__ X, const float* __restrict__ g,
    const float* __restrict__ b, float* __restrict__ Y,
    unsigned short* __restrict__ Yb) {
  const int wid = (blockIdx.x * blockDim.x + threadIdx.x) >> 6;
  const int lane = threadIdx.x & 63;
  const float* x = X + (size_t)wid * DMODEL;
  float4 v = *(const float4*)(x + lane * 4);
  float s = v.x + v.y + v.z + v.w;
  float s2 = v.x * v.x + v.y * v.y + v.z * v.z + v.w * v.w;
#pragma unroll
  for (int off = 32; off >= 1; off >>= 1) {
    s += __shfl_xor(s, off, 64);
    s2 += __shfl_xor(s2, off, 64);
  }
  const float mu = s * (1.f / DMODEL);
  const float var = s2 * (1.f / DMODEL) - mu * mu;
  const float inv = rsqrtf(var + LN_EPS);
  float4 gv = *(const float4*)(g + lane * 4);
  float4 bv = *(const float4*)(b + lane * 4);
  float4 o;
  o.x = (v.x - mu) * inv * gv.x + bv.x;
  o.y = (v.y - mu) * inv * gv.y + bv.y;
  o.z = (v.z - mu) * inv * gv.z + bv.z;
  o.w = (v.w - mu) * inv * gv.w + bv.w;
  if (Y) *(float4*)(Y + (size_t)wid * DMODEL + lane * 4) = o;
  if (Yb) {
    uint2 p;
    p.x = pk2(o.x, o.y);
    p.y = pk2(o.z, o.w);
    *(uint2*)(Yb + (size_t)wid * DMODEL + lane * 4) = p;
  }
}

extern "C" void kernel_launch(void* const* d_in, const int* in_sizes, int n_in,
                              void* d_out, int out_size, void* d_ws, size_t ws_size,
                              hipStream_t stream) {
  const float* x = (const float*)d_in[0];
  const float* g1 = (const float*)d_in[13];
  const float* b1 = (const float*)d_in[14];
  const float* g2 = (const float*)d_in[15];
  const float* b2 = (const float*)d_in[16];
  const float* g3 = (const float*)d_in[17];
  const float* b3 = (const float*)d_in[18];
  const float* g4 = (const float*)d_in[19];
  const float* b4 = (const float*)d_in[20];

  float* out = (float*)d_out;
  float* ws = (float*)d_ws;
  const size_t NM = (size_t)MROWS * DMODEL;
  const size_t ML = (size_t)32 * SEQ;  // 65536 rows per split
  const float QSCALE = 0.17677669529663687f * 1.4426950408889634f;

  float* F0 = ws;
  float* F1 = ws + NM;
  // union: fb bf16 8192x1024 (FFN) | oP fp32 2x65536x32 (attn) - disjoint
  char* U = (char*)(ws + 2 * NM);
  unsigned short* fb = (unsigned short*)U;
  float* oP = (float*)U;
  float* lP = ws + 4 * NM;  // 2 x 65536 fp32
  unsigned short* xb = (unsigned short*)(lP + 2 * ML);
  unsigned short* qb = xb + NM;
  unsigned short* kb = qb + NM;
  unsigned short* ob = kb + NM;
  unsigned short* nb = ob + NM;
  unsigned short* wb = nb + NM;
  unsigned short* qkv1 = wb;
  unsigned short* qkv2 = wb + 3 * 65536;
  unsigned short* o1w = wb + 6 * 65536;
  unsigned short* o2w = wb + 7 * 65536;
  unsigned short* f11 = wb + 8 * 65536;
  unsigned short* f21 = f11 + 262144;
  unsigned short* f12 = f21 + 262144;
  unsigned short* f22 = f12 + 262144;
  unsigned short* vt = (unsigned short*)F0;  // aliases F0 (dead then)

  {
    CvtArgs a;
    a.s[0] = x; a.d[0] = xb; a.n4[0] = (int)(NM / 4);
    unsigned short* wd[12] = {qkv1, qkv1 + 65536, qkv1 + 131072, o1w,
                              qkv2, qkv2 + 65536, qkv2 + 131072, o2w,
                              f11, f21, f12, f22};
    for (int i = 0; i < 12; i++) {
      a.s[i + 1] = (const float*)d_in[i + 1];
      a.d[i + 1] = wd[i];
      a.n4[i + 1] = (i < 8) ? 65536 / 4 : 262144 / 4;
    }
    cvt_kernel<<<dim3(256, 13), 256, 0, stream>>>(a);
  }

  auto gemm = [&](const unsigned short* A, const unsigned short* W,
                  const float* res, float* oF, unsigned short* oB,
                  unsigned short* oB2, unsigned short* oVT, float bs,
                  int N, int K) {
    const int ntx = N / 64;
    const int nwg = ntx * (MROWS / 64);
    gemm_bf16_kernel<<<nwg, 256, 0, stream>>>(A, W, res, oF, oB, oB2, oVT,
                                              bs, N, K, ntx);
  };
  auto attn = [&](const unsigned short* Q, const unsigned short* K,
                  const unsigned short* VT, unsigned short* O) {
    attn_mfma_kernel<<<dim3(SEQ / 128, 32, 2), 256, 0, stream>>>(
        Q, K, VT, oP, lP, SEQ / 2);
    attn_combine_kernel<<<65536 / 256, 256, 0, stream>>>(oP, lP, O);
  };
  auto ln = [&](const float* X, const float* gm, const float* bt, float* Y,
                unsigned short* Yb) {
    ln_kernel<<<MROWS / 4, 256, 0, stream>>>(X, gm, bt, Y, Yb);
  };

  // ---- Block 1 ----
  gemm(xb, qkv1, nullptr, nullptr, qb, kb, vt, QSCALE, 768, 256);  // QKV
  attn(qb, kb, vt, ob);
  gemm(ob, o1w, x, F0, nullptr, nullptr, nullptr, 1.f, 256, 256);  // x1
  ln(F0, g1, b1, F1, nb);
  gemm(nb, f11, nullptr, nullptr, fb, nullptr, nullptr, 1.f, 1024, 256);
  gemm(fb, f21, F1, F0, nullptr, nullptr, nullptr, 1.f, 256, 1024);
  ln(F0, g2, b2, F1, xb);

  // ---- Block 2 ----
  gemm(xb, qkv2, nullptr, nullptr, qb, kb, vt, QSCALE, 768, 256);
  attn(qb, kb, vt, ob);
  gemm(ob, o2w, F1, F0, nullptr, nullptr, nullptr, 1.f, 256, 256);
  ln(F0, g3, b3, F1, nb);
  gemm(nb, f12, nullptr, nullptr, fb, nullptr, nullptr, 1.f, 1024, 256);
  gemm(fb, f22, F1, F0, nullptr, nullptr, nullptr, 1.f, 256, 1024);
  ln(F0, g4, b4, out, nullptr);
}